// Round 1
// baseline (372.272 us; speedup 1.0000x reference)
//
#include <hip/hip_runtime.h>
#include <cstddef>

#define N_SAMPLES 16384
#define F_ 39
#define V_ 100000
#define E_ 16
#define H1_ 400
#define H2_ 400
#define FE_ (F_ * E_)  // 624

// ---- block-wide sum over 256 threads; result valid on threadIdx.x==0 ----
__device__ __forceinline__ float blockReduceSum256(float v, float* red) {
  int t = threadIdx.x;
  // wave-level butterfly (wave = 64 lanes on CDNA)
  v += __shfl_xor(v, 32);
  v += __shfl_xor(v, 16);
  v += __shfl_xor(v, 8);
  v += __shfl_xor(v, 4);
  v += __shfl_xor(v, 2);
  v += __shfl_xor(v, 1);
  if ((t & 63) == 0) red[t >> 6] = v;
  __syncthreads();
  if (t == 0) v = red[0] + red[1] + red[2] + red[3];
  return v;
}

// ---- pre1: colsum[f] = sum_n Xv[n,f]  (blocks 0..38)
//            w2red[k] = sum_j W2[k,j]*g2[j] (blocks 39..438)
__global__ __launch_bounds__(256) void pre1_kernel(
    const float* __restrict__ Xv, const float* __restrict__ W2,
    const float* __restrict__ g2, float* __restrict__ colsum,
    float* __restrict__ w2red) {
  __shared__ float red[4];
  int b = blockIdx.x, t = threadIdx.x;
  if (b < F_) {
    float acc = 0.f;
    for (int n = t; n < N_SAMPLES; n += 256) acc += Xv[(size_t)n * F_ + b];
    float tot = blockReduceSum256(acc, red);
    if (t == 0) colsum[b] = tot;
  } else {
    int k = b - F_;
    float acc = 0.f;
    for (int j = t; j < H2_; j += 256) acc += W2[k * H2_ + j] * g2[j];
    float tot = blockReduceSum256(acc, red);
    if (t == 0) w2red[k] = tot;
  }
}

// ---- pre2: A[m] = c^2 * sum_k W1[m,k]*g1[k]*w2red[k]  (blocks 0..623)
//            consts[0] = C_mlp                          (block 624)
__global__ __launch_bounds__(256) void pre2_kernel(
    const float* __restrict__ W1, const float* __restrict__ b1,
    const float* __restrict__ g1, const float* __restrict__ beta1,
    const float* __restrict__ b2, const float* __restrict__ g2,
    const float* __restrict__ beta2, const float* __restrict__ w2red,
    float* __restrict__ A, float* __restrict__ consts) {
  __shared__ float red[4];
  const float c = 1.0f / sqrtf(1.0f + 1e-5f);
  int b = blockIdx.x, t = threadIdx.x;
  if (b < FE_) {
    float acc = 0.f;
    for (int k = t; k < H1_; k += 256) acc += W1[b * H1_ + k] * g1[k] * w2red[k];
    float tot = blockReduceSum256(acc, red);
    if (t == 0) A[b] = c * c * tot;
  } else {
    // C_mlp = c^2*(b1*g1)·w2red + c*beta1·w2red + c*(g2·b2) + sum(beta2)
    float acc = 0.f;
    for (int k = t; k < H1_; k += 256) {
      float wr = w2red[k];
      acc += c * c * b1[k] * g1[k] * wr + c * beta1[k] * wr;
    }
    for (int j = t; j < H2_; j += 256) acc += c * g2[j] * b2[j] + beta2[j];
    float tot = blockReduceSum256(acc, red);
    if (t == 0) consts[0] = tot;
  }
}

// ---- main: 16 lanes per sample (lane j = embedding element),
//            16 samples per 256-thread block.
__global__ __launch_bounds__(256) void fused_main(
    const int* __restrict__ Xi, const float* __restrict__ Xv,
    const float* __restrict__ emb1, const float* __restrict__ emb2,
    const float* __restrict__ colsum, const float* __restrict__ A,
    const float* __restrict__ consts, const float* __restrict__ bias,
    float* __restrict__ out) {
  __shared__ int s_ix[16][F_ + 1];   // +1 pad: dodge bank aliasing
  __shared__ float s_xv[16][F_ + 1];
  __shared__ float s_A[FE_];
  __shared__ float s_cs[F_];
  int t = threadIdx.x;
  int n0 = blockIdx.x * 16;

  for (int i = t; i < FE_; i += 256) s_A[i] = A[i];
  if (t < F_) s_cs[t] = colsum[t];
  for (int i = t; i < 16 * F_; i += 256) {
    int smp = i / F_, f = i - smp * F_;
    s_ix[smp][f] = Xi[(n0 + smp) * F_ + f];
    s_xv[smp][f] = Xv[(n0 + smp) * F_ + f];
  }
  __syncthreads();

  int g = t >> 4;   // sample within block
  int j = t & 15;   // embedding element
  float s = 0.f, sq = 0.f, lin = 0.f, first = 0.f;

#pragma unroll
  for (int f = 0; f < F_; ++f) {
    int ix = s_ix[g][f];
    float v = s_xv[g][f];
    // 16 lanes read 16 consecutive floats => one 64B segment
    float x = emb2[((size_t)(f * V_ + ix)) * E_ + j] * v;
    s += x;
    sq += x * x;
    lin += x * s_A[f * E_ + j];
  }

  // first-order term: lane j covers features j, j+16, j+32
  for (int f = j; f < F_; f += E_) {
    first += emb1[(size_t)f * V_ + s_ix[g][f]] * s_cs[f];
  }

  // per-lane: FM second-order element contribution + linear + first partials
  float tv = 0.5f * (s * s - sq) + lin + first;
  // reduce across the 16 lanes of this sample's group
  tv += __shfl_xor(tv, 1);
  tv += __shfl_xor(tv, 2);
  tv += __shfl_xor(tv, 4);
  tv += __shfl_xor(tv, 8);

  if (j == 0) out[n0 + g] = tv + consts[0] + bias[0];
}

extern "C" void kernel_launch(void* const* d_in, const int* in_sizes, int n_in,
                              void* d_out, int out_size, void* d_ws, size_t ws_size,
                              hipStream_t stream) {
  const int* Xi = (const int*)d_in[0];
  const float* Xv = (const float*)d_in[1];
  const float* emb1 = (const float*)d_in[2];
  const float* emb2 = (const float*)d_in[3];
  const float* W1 = (const float*)d_in[4];
  const float* b1 = (const float*)d_in[5];
  const float* W2 = (const float*)d_in[6];
  const float* b2 = (const float*)d_in[7];
  const float* g1 = (const float*)d_in[8];
  const float* beta1 = (const float*)d_in[9];
  const float* g2 = (const float*)d_in[10];
  const float* beta2 = (const float*)d_in[11];
  const float* bias = (const float*)d_in[12];
  float* out = (float*)d_out;

  float* ws = (float*)d_ws;
  float* colsum = ws;         // 39 (round to 64)
  float* w2red = ws + 64;     // 400 (round to 448)
  float* A = ws + 512;        // 624
  float* consts = ws + 1152;  // 1

  pre1_kernel<<<F_ + H1_, 256, 0, stream>>>(Xv, W2, g2, colsum, w2red);
  pre2_kernel<<<FE_ + 1, 256, 0, stream>>>(W1, b1, g1, beta1, b2, g2, beta2,
                                           w2red, A, consts);
  fused_main<<<N_SAMPLES / 16, 256, 0, stream>>>(Xi, Xv, emb1, emb2, colsum, A,
                                                 consts, bias, out);
}